// Round 3
// baseline (82.346 us; speedup 1.0000x reference)
//
#include <hip/hip_runtime.h>

#define B_DIM 8192
#define C_DIM 4096
#define NBLOCKS 2048
#define NTHREADS 256

// log2 clamp equivalent of max(ln(x), -100):  -100/ln(2)
#define LOG2_CLAMP (-144.26950408889634f)
#define LN2 0.6931471805599453f

__device__ __forceinline__ void sq_terms(float o, float oc, float& acc_u2, float& acc_d2) {
    float s0 = (o > 0.5f) ? 1.0f : 0.0f;
    float u  = o - s0;                    // o - round-to-side
    float sh = fmaf(-0.25f, u, o);        // sharp
    float d2 = oc - sh;
    acc_u2 = fmaf(u, u, acc_u2);          // (o-sharp)^2 = (u/4)^2, scaled later
    acc_d2 = fmaf(d2, d2, acc_d2);
}

__device__ __forceinline__ float bce_group(float4 o, float4 l) {
    // returns sum over 4 elems of  l*log2(p) + (1-l)*log2(1-p)
    float bb = 0.0f;
    {
        float lp = fmaxf(__log2f(o.x), LOG2_CLAMP);
        float lq = fmaxf(__log2f(1.0f - o.x), LOG2_CLAMP);
        bb = fmaf(l.x, lp - lq, bb + lq);
    }
    {
        float lp = fmaxf(__log2f(o.y), LOG2_CLAMP);
        float lq = fmaxf(__log2f(1.0f - o.y), LOG2_CLAMP);
        bb = fmaf(l.y, lp - lq, bb + lq);
    }
    {
        float lp = fmaxf(__log2f(o.z), LOG2_CLAMP);
        float lq = fmaxf(__log2f(1.0f - o.z), LOG2_CLAMP);
        bb = fmaf(l.z, lp - lq, bb + lq);
    }
    {
        float lp = fmaxf(__log2f(o.w), LOG2_CLAMP);
        float lq = fmaxf(__log2f(1.0f - o.w), LOG2_CLAMP);
        bb = fmaf(l.w, lp - lq, bb + lq);
    }
    return bb;
}

__global__ __launch_bounds__(NTHREADS) void semiloss_kernel(
        const float* __restrict__ out,
        const float* __restrict__ cons,
        const float* __restrict__ lab,
        const int* __restrict__ source,
        float* __restrict__ dout)
{
    const unsigned n4     = (unsigned)B_DIM * (unsigned)C_DIM / 4u;  // 8,388,608
    const unsigned stride = NBLOCKS * NTHREADS;                      // 524,288
    unsigned tid = blockIdx.x * (unsigned)NTHREADS + threadIdx.x;

    const float4* __restrict__ o4 = (const float4*)out;
    const float4* __restrict__ c4 = (const float4*)cons;
    const float4* __restrict__ l4 = (const float4*)lab;

    float acc_b  = 0.0f;   // masked sum of l*log2(p)+(1-l)*log2(1-p)
    float acc_u2 = 0.0f;
    float acc_d2 = 0.0f;

    // exact: n4 == 16 * stride, unroll x2 -> 8 outer iterations
    #pragma unroll 2
    for (unsigned i = tid; i < n4; i += 2u * stride) {
        unsigned i2 = i + stride;

        // issue ALL loads up front (no branches -> max loads in flight)
        float4 oA = o4[i];
        float4 oB = o4[i2];
        float4 cA = c4[i];
        float4 cB = c4[i2];
        float4 lA = l4[i];
        float4 lB = l4[i2];
        int sA = source[i  >> 10];    // 1024 float4s per row; wave-uniform
        int sB = source[i2 >> 10];
        float mA = ((unsigned)sA <= 1u) ? 1.0f : 0.0f;
        float mB = ((unsigned)sB <= 1u) ? 1.0f : 0.0f;

        sq_terms(oA.x, cA.x, acc_u2, acc_d2);
        sq_terms(oA.y, cA.y, acc_u2, acc_d2);
        sq_terms(oA.z, cA.z, acc_u2, acc_d2);
        sq_terms(oA.w, cA.w, acc_u2, acc_d2);
        sq_terms(oB.x, cB.x, acc_u2, acc_d2);
        sq_terms(oB.y, cB.y, acc_u2, acc_d2);
        sq_terms(oB.z, cB.z, acc_u2, acc_d2);
        sq_terms(oB.w, cB.w, acc_u2, acc_d2);

        acc_b = fmaf(mA, bce_group(oA, lA), acc_b);
        acc_b = fmaf(mB, bce_group(oB, lB), acc_b);
    }

    // combine: bce = -ln2 * acc_b ; pseudo = 0.0625*acc_u2 ; cons = acc_d2
    float acc = fmaf(-LN2, acc_b, fmaf(0.0625f, acc_u2, acc_d2));

    // wave (64-lane) reduction
    #pragma unroll
    for (int off = 32; off > 0; off >>= 1)
        acc += __shfl_down(acc, off, 64);

    __shared__ float red[NTHREADS / 64];
    int lane = threadIdx.x & 63;
    int wave = threadIdx.x >> 6;
    if (lane == 0) red[wave] = acc;
    __syncthreads();

    if (threadIdx.x == 0) {
        float s = 0.0f;
        #pragma unroll
        for (int w = 0; w < NTHREADS / 64; ++w) s += red[w];
        atomicAdd(dout, s * (1.0f / (float)B_DIM));   // device-scope by default
    }
}

extern "C" void kernel_launch(void* const* d_in, const int* in_sizes, int n_in,
                              void* d_out, int out_size, void* d_ws, size_t ws_size,
                              hipStream_t stream) {
    const float* out  = (const float*)d_in[0];
    const float* cons = (const float*)d_in[1];
    const float* lab  = (const float*)d_in[2];
    const int*   src  = (const int*)d_in[3];
    float* dout = (float*)d_out;

    // zero the accumulator every call (captured into the graph -> replay-safe)
    hipMemsetAsync(dout, 0, sizeof(float), stream);
    semiloss_kernel<<<NBLOCKS, NTHREADS, 0, stream>>>(out, cons, lab, src, dout);
}

// Round 4
// 80.761 us; speedup vs baseline: 1.0196x; 1.0196x over previous
//
#include <hip/hip_runtime.h>

#define B_DIM 8192
#define C_DIM 4096
#define NBLOCKS 2048
#define NTHREADS 256

// log2 clamp equivalent of max(ln(x), -100):  -100/ln(2)
#define LOG2_CLAMP (-144.26950408889634f)
#define LN2 0.6931471805599453f

__device__ __forceinline__ void sq_terms(float o, float oc, float& acc_u2, float& acc_d2) {
    float s0 = (o > 0.5f) ? 1.0f : 0.0f;
    float u  = o - s0;                    // o - (o>0.5)
    float sh = fmaf(-0.25f, u, o);        // sharp
    float d2 = oc - sh;
    acc_u2 = fmaf(u, u, acc_u2);          // (o-sharp)^2 = u^2/16, scaled at end
    acc_d2 = fmaf(d2, d2, acc_d2);
}

__device__ __forceinline__ float bce_group(float4 o, float4 l) {
    // sum over 4 elems of  l*log2(p) + (1-l)*log2(1-p)
    float bb = 0.0f;
    {
        float lp = fmaxf(__log2f(o.x), LOG2_CLAMP);
        float lq = fmaxf(__log2f(1.0f - o.x), LOG2_CLAMP);
        bb = fmaf(l.x, lp - lq, bb + lq);
    }
    {
        float lp = fmaxf(__log2f(o.y), LOG2_CLAMP);
        float lq = fmaxf(__log2f(1.0f - o.y), LOG2_CLAMP);
        bb = fmaf(l.y, lp - lq, bb + lq);
    }
    {
        float lp = fmaxf(__log2f(o.z), LOG2_CLAMP);
        float lq = fmaxf(__log2f(1.0f - o.z), LOG2_CLAMP);
        bb = fmaf(l.z, lp - lq, bb + lq);
    }
    {
        float lp = fmaxf(__log2f(o.w), LOG2_CLAMP);
        float lq = fmaxf(__log2f(1.0f - o.w), LOG2_CLAMP);
        bb = fmaf(l.w, lp - lq, bb + lq);
    }
    return bb;
}

__global__ __launch_bounds__(NTHREADS) void semiloss_kernel(
        const float* __restrict__ out,
        const float* __restrict__ cons,
        const float* __restrict__ lab,
        const int* __restrict__ source,
        float* __restrict__ dout)
{
    const unsigned n4 = (unsigned)B_DIM * (unsigned)C_DIM / 4u;      // 8,388,608 float4s
    const unsigned stride2 = 2u * NBLOCKS * NTHREADS;                // 1,048,576 (in float4s)
    unsigned j = 2u * (blockIdx.x * (unsigned)NTHREADS + threadIdx.x);

    const float4* __restrict__ o4 = (const float4*)out;
    const float4* __restrict__ c4 = (const float4*)cons;
    const float4* __restrict__ l4 = (const float4*)lab;

    float acc_b  = 0.0f;   // masked sum of l*log2(p)+(1-l)*log2(1-p)
    float acc_u2 = 0.0f;
    float acc_d2 = 0.0f;

    // exact: n4 == 8 * stride2 -> 8 iterations, each thread owns 2 consecutive float4s
    for (unsigned it = 0; it < 8u; ++it, j += stride2) {
        // all loads from only 3 contiguous streams + source; issue together
        float4 oA = o4[j];
        float4 oB = o4[j + 1];
        float4 cA = c4[j];
        float4 cB = c4[j + 1];
        float4 lA = l4[j];
        float4 lB = l4[j + 1];
        int s = source[j >> 10];          // both halves in same row (j even)
        float m = ((unsigned)s <= 1u) ? 1.0f : 0.0f;

        sq_terms(oA.x, cA.x, acc_u2, acc_d2);
        sq_terms(oA.y, cA.y, acc_u2, acc_d2);
        sq_terms(oA.z, cA.z, acc_u2, acc_d2);
        sq_terms(oA.w, cA.w, acc_u2, acc_d2);
        sq_terms(oB.x, cB.x, acc_u2, acc_d2);
        sq_terms(oB.y, cB.y, acc_u2, acc_d2);
        sq_terms(oB.z, cB.z, acc_u2, acc_d2);
        sq_terms(oB.w, cB.w, acc_u2, acc_d2);

        float bb = bce_group(oA, lA) + bce_group(oB, lB);
        acc_b = fmaf(m, bb, acc_b);
    }

    // combine: bce = -ln2 * acc_b ; pseudo = 0.0625*acc_u2 ; cons = acc_d2
    float acc = fmaf(-LN2, acc_b, fmaf(0.0625f, acc_u2, acc_d2));

    // wave (64-lane) reduction
    #pragma unroll
    for (int off = 32; off > 0; off >>= 1)
        acc += __shfl_down(acc, off, 64);

    __shared__ float red[NTHREADS / 64];
    int lane = threadIdx.x & 63;
    int wave = threadIdx.x >> 6;
    if (lane == 0) red[wave] = acc;
    __syncthreads();

    if (threadIdx.x == 0) {
        float s = 0.0f;
        #pragma unroll
        for (int w = 0; w < NTHREADS / 64; ++w) s += red[w];
        atomicAdd(dout, s * (1.0f / (float)B_DIM));   // device-scope by default
    }
}

extern "C" void kernel_launch(void* const* d_in, const int* in_sizes, int n_in,
                              void* d_out, int out_size, void* d_ws, size_t ws_size,
                              hipStream_t stream) {
    const float* out  = (const float*)d_in[0];
    const float* cons = (const float*)d_in[1];
    const float* lab  = (const float*)d_in[2];
    const int*   src  = (const int*)d_in[3];
    float* dout = (float*)d_out;

    hipMemsetAsync(dout, 0, sizeof(float), stream);   // graph-capture legal
    semiloss_kernel<<<NBLOCKS, NTHREADS, 0, stream>>>(out, cons, lab, src, dout);
}